// Round 6
// baseline (342.140 us; speedup 1.0000x reference)
//
#include <hip/hip_runtime.h>
#include <hip/hip_bf16.h>
#include <math.h>

#define BB 2
#define CC 256
#define CMID 16
#define HH 96
#define WW 96
#define HWSZ (HH*WW)
#define SH 48
#define SHSZ (SH*SH)
#define MMK 7
#define HO 90
#define WO 90
#define NPATCH (HO*WO)
#define NSITE (BB*CMID*NPATCH)

typedef __hip_bfloat16 bf16;

__device__ __forceinline__ float ldf(const bf16* p){ return __bfloat162float(*p); }
__device__ __forceinline__ float ldf(const float* p){ return *p; }
__device__ __forceinline__ void stf(bf16* p, float v){ *p = __float2bfloat16(v); }
__device__ __forceinline__ void stf(float* p, float v){ *p = v; }

// ---------------- dtype detect: 1 = inputs are fp32, 0 = inputs are bf16.
// Reading fp32 gaussian data as bf16 halves: the low half's exponent field is
// fp32 mantissa bits (~uniform) -> ~0.4% decode as exp==0xFF. True bf16
// gaussian data (|v|<~7) never has exp 0xFF.
__global__ void k_detect(const unsigned short* __restrict__ bits, int* __restrict__ flag) {
    __shared__ int cnt;
    if (threadIdx.x == 0) cnt = 0;
    __syncthreads();
    int c = 0;
    for (int i = threadIdx.x; i < 65536; i += 256)
        if (((bits[i] >> 7) & 0xFF) == 0xFF) c++;
    if (c) atomicAdd(&cnt, c);
    __syncthreads();
    if (threadIdx.x == 0) *flag = (cnt > 0) ? 1 : 0;
}

// ---------------- bilinear upsample coords (exact dyadic arithmetic; bit-
// reproducible across both call sites, matching the reference's fp32 math)
struct BiC { int r0, r1; float wr; };
__device__ __forceinline__ BiC bic(int y) {
    float sy = fminf(fmaxf((y + 0.5f) * 0.5f - 0.5f, 0.f), 47.f);
    BiC b; b.r0 = (int)sy; b.r1 = min(b.r0 + 1, 47); b.wr = sy - (float)b.r0;
    return b;
}
template<typename T>
__device__ __forceinline__ float upsamp(const T* __restrict__ plane, BiC ry, BiC rx) {
    float v00 = ldf(plane + ry.r0 * SH + rx.r0);
    float v01 = ldf(plane + ry.r0 * SH + rx.r1);
    float v10 = ldf(plane + ry.r1 * SH + rx.r0);
    float v11 = ldf(plane + ry.r1 * SH + rx.r1);
    float row0 = v00 * (1.f - ry.wr) + v10 * ry.wr;   // reference order: rows first
    float row1 = v01 * (1.f - ry.wr) + v11 * ry.wr;
    return row0 * (1.f - rx.wr) + row1 * rx.wr;
}

// ---------------- K1a: xl(b,o,hw) = sum_c x_low(b,c,hw) * w_low(o,c)
template<typename T, int FLAGV>
__global__ __launch_bounds__(256) void k_proj_low(const T* __restrict__ src,
                                                  const T* __restrict__ wmat,
                                                  float* __restrict__ dst,
                                                  const int* __restrict__ flag) {
    if (*flag != FLAGV) return;
    __shared__ float wsm[CMID * CC];
    for (int t = threadIdx.x; t < CMID * CC; t += 256) wsm[t] = ldf(wmat + t);
    __syncthreads();
    int t = blockIdx.x * 256 + threadIdx.x;
    if (t >= BB * HWSZ) return;
    int b = t / HWSZ, hw = t % HWSZ;
    const T* sp = src + (size_t)b * CC * HWSZ + hw;
    float acc[CMID];
#pragma unroll
    for (int o = 0; o < CMID; o++) acc[o] = 0.f;
    for (int c = 0; c < CC; c++) {
        float v = ldf(sp + (size_t)c * HWSZ);
#pragma unroll
        for (int o = 0; o < CMID; o++) acc[o] = fmaf(v, wsm[o * CC + c], acc[o]);
    }
    float* dp = dst + (size_t)b * CMID * HWSZ + hw;
#pragma unroll
    for (int o = 0; o < CMID; o++) dp[o * HWSZ] = acc[o];
}

// ---------------- K1b: xh(b,o,hw) = sum_c upsample(x_high)(b,c,hw) * w_high(o,c)
template<typename T, int FLAGV>
__global__ __launch_bounds__(256) void k_proj_high(const T* __restrict__ xhigh,
                                                   const T* __restrict__ wmat,
                                                   float* __restrict__ dst,
                                                   const int* __restrict__ flag) {
    if (*flag != FLAGV) return;
    __shared__ float wsm[CMID * CC];
    for (int t = threadIdx.x; t < CMID * CC; t += 256) wsm[t] = ldf(wmat + t);
    __syncthreads();
    int t = blockIdx.x * 256 + threadIdx.x;
    if (t >= BB * HWSZ) return;
    int b = t / HWSZ, hw = t % HWSZ;
    int x = hw % WW, y = hw / WW;
    BiC ry = bic(y), rx = bic(x);
    const T* sp = xhigh + (size_t)b * CC * SHSZ;
    float acc[CMID];
#pragma unroll
    for (int o = 0; o < CMID; o++) acc[o] = 0.f;
    for (int c = 0; c < CC; c++) {
        float v = upsamp(sp + (size_t)c * SHSZ, ry, rx);
#pragma unroll
        for (int o = 0; o < CMID; o++) acc[o] = fmaf(v, wsm[o * CC + c], acc[o]);
    }
    float* dp = dst + (size_t)b * CMID * HWSZ + hw;
#pragma unroll
    for (int o = 0; o < CMID; o++) dp[o * HWSZ] = acc[o];
}

// ---------------- direction estimate (replicates the reference's fftshift
// indexing quirk: shifted-mag scored with unshifted rho/theta tables)
__device__ float estimate_dir(const float* __restrict__ p) {
    float pv[49];
#pragma unroll
    for (int r = 0; r < 7; r++)
#pragma unroll
        for (int c = 0; c < 7; c++) pv[r * 7 + c] = p[r * WW + c];

    constexpr float TRE[7] = {1.f, 0.6234898019f, -0.2225209340f, -0.9009688679f,
                              -0.9009688679f, -0.2225209340f, 0.6234898019f};
    constexpr float TIM[7] = {0.f, -0.7818314825f, -0.9749279122f, -0.4338837391f,
                              0.4338837391f, 0.9749279122f, 0.7818314825f};
    constexpr float FS[7] = {3.f, -3.f, -2.f, -1.f, 0.f, 1.f, 2.f}; // f[(t+3)%7]

    float best = -1.f;
    int bk = 0;
#pragma unroll
    for (int u = 0; u < 4; u++) {  // Hermitian symmetry: u=0..3 suffices
        float Ar[7], Ai[7];
#pragma unroll
        for (int c = 0; c < 7; c++) { Ar[c] = 0.f; Ai[c] = 0.f; }
#pragma unroll
        for (int r = 0; r < 7; r++) {
            const int t = (u * r) % 7;
            const float wre = TRE[t], wim = TIM[t];
#pragma unroll
            for (int c = 0; c < 7; c++) {
                float v = pv[r * 7 + c];
                Ar[c] = fmaf(v, wre, Ar[c]);
                Ai[c] = fmaf(v, wim, Ai[c]);
            }
        }
#pragma unroll
        for (int v = 0; v < 7; v++) {
            if (u == 0 && v >= 4) continue;  // row-0 conjugates live within the row
            float Fr = 0.f, Fi = 0.f;
#pragma unroll
            for (int c = 0; c < 7; c++) {
                const int t = (v * c) % 7;
                Fr += Ar[c] * TRE[t] - Ai[c] * TIM[t];
                Fi += Ar[c] * TIM[t] + Ai[c] * TRE[t];
            }
            float mag = sqrtf(Fr * Fr + Fi * Fi) * (1.f / 7.f) + 1e-8f;
            {
                const int k1 = ((u + 3) % 7) * 7 + ((v + 3) % 7);
                if (k1 != 0) {
                    float s = mag * sqrtf(FS[u] * FS[u] + FS[v] * FS[v]);
                    if (s > best || (s == best && k1 < bk)) { best = s; bk = k1; }
                }
            }
            const int u2 = (7 - u) % 7, v2 = (7 - v) % 7;
            if (u2 != u || v2 != v) {  // conjugate: same mag, different rho/k
                const int k2 = ((u2 + 3) % 7) * 7 + ((v2 + 3) % 7);
                if (k2 != 0) {
                    float s = mag * sqrtf(FS[u2] * FS[u2] + FS[v2] * FS[v2]);
                    if (s > best || (s == best && k2 < bk)) { best = s; bk = k2; }
                }
            }
        }
    }
    int bi = bk / 7, bj = bk % 7;
    float fi = (float)(bi <= 3 ? bi : bi - 7);
    float fj = (float)(bj <= 3 ? bj : bj - 7);
    float th = atan2f(fi, fj);
    if (th < 0.f) th += 6.28318530717958647692f;
    const float PI_F = 3.14159265358979323846f;
    if (th >= PI_F) th -= PI_F;
    return th;
}

// ---------------- K2: per-site rotation angle -> cos/sin (dtype-independent)
__global__ __launch_bounds__(256) void k_theta(const float* __restrict__ xl,
                                               const float* __restrict__ xh,
                                               float* __restrict__ cosd,
                                               float* __restrict__ sind) {
    int s = blockIdx.x * 256 + threadIdx.x;
    if (s >= NSITE) return;
    int n = s % NPATCH;
    int bcm = s / NPATCH;
    int py = n / WO, px = n % WO;
    size_t off = (size_t)bcm * HWSZ + py * WW + px;
    float tl = estimate_dir(xl + off);
    float th = estimate_dir(xh + off);
    float d = tl - th;
    cosd[s] = cosf(d);
    sind[s] = sinf(d);
}

// ---------------- K3: gather-fold rotated patches -> aligned (dtype-independent)
__global__ __launch_bounds__(256) void k_fold(const float* __restrict__ xh,
                                              const float* __restrict__ cosd,
                                              const float* __restrict__ sind,
                                              float* __restrict__ alg) {
    int idx = blockIdx.x * 256 + threadIdx.x;
    if (idx >= BB * CMID * HWSZ) return;
    int x = idx % WW;
    int y = (idx / WW) % HH;
    int bcm = idx / HWSZ;
    const float* hp = xh + (size_t)bcm * HWSZ;
    const float* cb = cosd + (size_t)bcm * NPATCH;
    const float* sb = sind + (size_t)bcm * NPATCH;
    float acc = 0.f;
    int ilo = max(0, y - (HO - 1)), ihi = min(MMK - 1, y);
    int jlo = max(0, x - (WO - 1)), jhi = min(MMK - 1, x);
    for (int i = ilo; i <= ihi; i++) {
        int py = y - i;
        float by = -1.f + (2.f * i + 1.f) / 7.f;
        for (int j = jlo; j <= jhi; j++) {
            int px = x - j;
            int n = py * WO + px;
            float cs = cb[n], sn = sb[n];
            float tx = 3.f - cs * 3.f + sn * 3.f;
            float ty = 3.f - sn * 3.f - cs * 3.f;
            float bx = -1.f + (2.f * j + 1.f) / 7.f;
            float gx = cs * bx - sn * by + tx;
            float gy = sn * bx + cs * by + ty;
            float ix = ((gx + 1.f) * 7.f - 1.f) * 0.5f;
            float iy = ((gy + 1.f) * 7.f - 1.f) * 0.5f;
            float x0 = floorf(ix), y0 = floorf(iy);
#pragma unroll
            for (int dy = 0; dy < 2; dy++)
#pragma unroll
                for (int dx = 0; dx < 2; dx++) {
                    float xc = x0 + dx, yc = y0 + dy;
                    if (xc >= 0.f && xc <= 6.f && yc >= 0.f && yc <= 6.f) {
                        float wgt = (1.f - fabsf(ix - xc)) * (1.f - fabsf(iy - yc));
                        acc = fmaf(hp[(py + (int)yc) * WW + (px + (int)xc)], wgt, acc);
                    }
                }
        }
    }
    float cy = fminf(fminf((float)(y + 1), 7.f), fminf((float)(HH - y), (float)(HH - MMK + 1)));
    float cx = fminf(fminf((float)(x + 1), 7.f), fminf((float)(WW - x), (float)(WW - MMK + 1)));
    alg[idx] = acc / (cy * cx + 1e-8f);
}

// ---------------- K4: out = x_low + ls * (w_recon . aligned) + upsample(x_high)
template<typename T, typename OT, int FLAGV>
__global__ __launch_bounds__(256) void k_final(const T* __restrict__ x_low,
                                               const T* __restrict__ x_high,
                                               const float* __restrict__ alg,
                                               const T* __restrict__ wrec,
                                               const T* __restrict__ lscale,
                                               OT* __restrict__ out,
                                               const int* __restrict__ flag) {
    if (*flag != FLAGV) return;
    int idx = blockIdx.x * 256 + threadIdx.x;
    if (idx >= BB * CC * HWSZ) return;
    int hw = idx % HWSZ;
    int c = (idx / HWSZ) % CC;
    int b = idx / (CC * HWSZ);
    int x = hw % WW, y = hw / WW;
    const float* ap = alg + (size_t)b * CMID * HWSZ + hw;
    float rec = 0.f;
#pragma unroll
    for (int o = 0; o < CMID; o++)
        rec = fmaf(ap[o * HWSZ], ldf(wrec + c * CMID + o), rec);
    float upv = upsamp(x_high + ((size_t)b * CC + c) * SHSZ, bic(y), bic(x));
    float ls = ldf(lscale);
    float v = ldf(x_low + idx) + ls * rec;   // reference order: (x_low + ls*rec) + up
    stf(out + idx, v + upv);
}

extern "C" void kernel_launch(void* const* d_in, const int* in_sizes, int n_in,
                              void* d_out, int out_size, void* d_ws, size_t ws_size,
                              hipStream_t stream) {
    int* flag = (int*)d_ws;
    float* base = (float*)d_ws + 4;                 // 16-byte offset
    float* xl   = base;                             // 294,912 f
    float* xh   = xl + (size_t)BB * CMID * HWSZ;    // 294,912 f
    float* cosd = xh + (size_t)BB * CMID * HWSZ;    // 259,200 f
    float* sind = cosd + NSITE;                     // 259,200 f
    float* alg  = sind + NSITE;                     // 294,912 f   (total ~5.6 MB)

    k_detect<<<1, 256, 0, stream>>>((const unsigned short*)d_in[0], flag);

    const int gp = (BB * HWSZ + 255) / 256;
    const int gf = (BB * CC * HWSZ + 255) / 256;

    // bf16-input variant (flag==0)
    k_proj_low<bf16, 0><<<gp, 256, 0, stream>>>((const bf16*)d_in[1], (const bf16*)d_in[2], xl, flag);
    k_proj_high<bf16, 0><<<gp, 256, 0, stream>>>((const bf16*)d_in[0], (const bf16*)d_in[3], xh, flag);
    // fp32-input variant (flag==1)
    k_proj_low<float, 1><<<gp, 256, 0, stream>>>((const float*)d_in[1], (const float*)d_in[2], xl, flag);
    k_proj_high<float, 1><<<gp, 256, 0, stream>>>((const float*)d_in[0], (const float*)d_in[3], xh, flag);

    k_theta<<<(NSITE + 255) / 256, 256, 0, stream>>>(xl, xh, cosd, sind);
    k_fold<<<(BB * CMID * HWSZ + 255) / 256, 256, 0, stream>>>(xh, cosd, sind, alg);

    k_final<bf16, bf16, 0><<<gf, 256, 0, stream>>>((const bf16*)d_in[1], (const bf16*)d_in[0], alg,
                                                   (const bf16*)d_in[4], (const bf16*)d_in[5],
                                                   (bf16*)d_out, flag);
    k_final<float, float, 1><<<gf, 256, 0, stream>>>((const float*)d_in[1], (const float*)d_in[0], alg,
                                                     (const float*)d_in[4], (const float*)d_in[5],
                                                     (float*)d_out, flag);
}

// Round 7
// 307.452 us; speedup vs baseline: 1.1128x; 1.1128x over previous
//
#include <hip/hip_runtime.h>
#include <hip/hip_bf16.h>
#include <math.h>

#define BB 2
#define CC 256
#define CMID 16
#define HH 96
#define WW 96
#define HWSZ (HH*WW)
#define SH 48
#define SHSZ (SH*SH)
#define MMK 7
#define HO 90
#define WO 90
#define NPATCH (HO*WO)
#define NSITE (BB*CMID*NPATCH)
#define NPIX (BB*HWSZ)          // 18432 projection pixels
#define PBLK 288                // NPIX / 64

typedef __hip_bfloat16 bf16;

__device__ __forceinline__ float ldf(const bf16* p){ return __bfloat162float(*p); }
__device__ __forceinline__ float ldf(const float* p){ return *p; }
__device__ __forceinline__ void stf(bf16* p, float v){ *p = __float2bfloat16(v); }
__device__ __forceinline__ void stf(float* p, float v){ *p = v; }

// ---------------- dtype detect: 1 = inputs are fp32, 0 = inputs are bf16.
__global__ void k_detect(const unsigned short* __restrict__ bits, int* __restrict__ flag) {
    __shared__ int cnt;
    if (threadIdx.x == 0) cnt = 0;
    __syncthreads();
    int c = 0;
    for (int i = threadIdx.x; i < 65536; i += 256)
        if (((bits[i] >> 7) & 0xFF) == 0xFF) c++;
    if (c) atomicAdd(&cnt, c);
    __syncthreads();
    if (threadIdx.x == 0) *flag = (cnt > 0) ? 1 : 0;
}

// ---------------- bilinear coords (exact dyadic arithmetic, reference order)
struct BiC { int r0, r1; float wr; };
__device__ __forceinline__ BiC bic(int y) {
    float sy = fminf(fmaxf((y + 0.5f) * 0.5f - 0.5f, 0.f), 47.f);
    BiC b; b.r0 = (int)sy; b.r1 = min(b.r0 + 1, 47); b.wr = sy - (float)b.r0;
    return b;
}
template<typename T>
__device__ __forceinline__ float upsamp(const T* __restrict__ plane, BiC ry, BiC rx) {
    float v00 = ldf(plane + ry.r0 * SH + rx.r0);
    float v01 = ldf(plane + ry.r0 * SH + rx.r1);
    float v10 = ldf(plane + ry.r1 * SH + rx.r0);
    float v11 = ldf(plane + ry.r1 * SH + rx.r1);
    float row0 = v00 * (1.f - ry.wr) + v10 * ry.wr;   // reference order: rows first
    float row1 = v01 * (1.f - ry.wr) + v11 * ry.wr;
    return row0 * (1.f - rx.wr) + row1 * rx.wr;
}

// ---------------- K1a: xl partials. grid 2*PBLK x 64 threads; block half
// (blockIdx/PBLK) sums channels [half*128, half*128+128) into its PRIVATE
// dst buffer (no atomics, no cross-thread reduce). k_add merges halves.
template<typename T, int FLAGV>
__global__ __launch_bounds__(64) void k_proj_low(const T* __restrict__ src,
                                                 const T* __restrict__ wmat,
                                                 float* __restrict__ dst0,
                                                 float* __restrict__ dst1,
                                                 const int* __restrict__ flag) {
    if (*flag != FLAGV) return;
    const int half = blockIdx.x / PBLK;
    const int c0   = half * 128;
    float* dst = half ? dst1 : dst0;
    __shared__ float wsm[CMID * 128];   // 8 KB: this half's weights
    for (int t = threadIdx.x; t < CMID * 128; t += 64)
        wsm[t] = ldf(wmat + (t >> 7) * CC + c0 + (t & 127));
    __syncthreads();
    const int px = (blockIdx.x % PBLK) * 64 + threadIdx.x;   // < NPIX exactly
    const int b = px / HWSZ, hw = px % HWSZ;
    const T* sp = src + (size_t)b * CC * HWSZ + hw;
    float acc[CMID];
#pragma unroll
    for (int o = 0; o < CMID; o++) acc[o] = 0.f;
    for (int c = 0; c < 128; c++) {
        float v = ldf(sp + (size_t)(c0 + c) * HWSZ);
#pragma unroll
        for (int o = 0; o < CMID; o++) acc[o] = fmaf(v, wsm[o * 128 + c], acc[o]);
    }
    float* dp = dst + (size_t)b * CMID * HWSZ + hw;
#pragma unroll
    for (int o = 0; o < CMID; o++) dp[o * HWSZ] = acc[o];
}

// ---------------- K1b: xh partials = sum_c upsample(x_high)(c) * w_high(o,c)
template<typename T, int FLAGV>
__global__ __launch_bounds__(64) void k_proj_high(const T* __restrict__ xhigh,
                                                  const T* __restrict__ wmat,
                                                  float* __restrict__ dst0,
                                                  float* __restrict__ dst1,
                                                  const int* __restrict__ flag) {
    if (*flag != FLAGV) return;
    const int half = blockIdx.x / PBLK;
    const int c0   = half * 128;
    float* dst = half ? dst1 : dst0;
    __shared__ float wsm[CMID * 128];
    for (int t = threadIdx.x; t < CMID * 128; t += 64)
        wsm[t] = ldf(wmat + (t >> 7) * CC + c0 + (t & 127));
    __syncthreads();
    const int px = (blockIdx.x % PBLK) * 64 + threadIdx.x;
    const int b = px / HWSZ, hw = px % HWSZ;
    const int x = hw % WW, y = hw / WW;
    BiC ry = bic(y), rx = bic(x);
    const T* sp = xhigh + (size_t)b * CC * SHSZ + (size_t)c0 * SHSZ;
    float acc[CMID];
#pragma unroll
    for (int o = 0; o < CMID; o++) acc[o] = 0.f;
    for (int c = 0; c < 128; c++) {
        float v = upsamp(sp + (size_t)c * SHSZ, ry, rx);
#pragma unroll
        for (int o = 0; o < CMID; o++) acc[o] = fmaf(v, wsm[o * 128 + c], acc[o]);
    }
    float* dp = dst + (size_t)b * CMID * HWSZ + hw;
#pragma unroll
    for (int o = 0; o < CMID; o++) dp[o * HWSZ] = acc[o];
}

// ---------------- K1c: merge partials: xl += xl_p1, xh += xh_p1
__global__ __launch_bounds__(256) void k_add(float* __restrict__ xl,
                                             const float* __restrict__ xl_p1,
                                             float* __restrict__ xh,
                                             const float* __restrict__ xh_p1) {
    int idx = blockIdx.x * 256 + threadIdx.x;
    if (idx >= BB * CMID * HWSZ) return;
    xl[idx] = xl[idx] + xl_p1[idx];
    xh[idx] = xh[idx] + xh_p1[idx];
}

// ---------------- direction estimate (replicates the reference's fftshift
// indexing quirk: shifted-mag scored with unshifted rho/theta tables)
__device__ float estimate_dir(const float* __restrict__ p) {
    float pv[49];
#pragma unroll
    for (int r = 0; r < 7; r++)
#pragma unroll
        for (int c = 0; c < 7; c++) pv[r * 7 + c] = p[r * WW + c];

    constexpr float TRE[7] = {1.f, 0.6234898019f, -0.2225209340f, -0.9009688679f,
                              -0.9009688679f, -0.2225209340f, 0.6234898019f};
    constexpr float TIM[7] = {0.f, -0.7818314825f, -0.9749279122f, -0.4338837391f,
                              0.4338837391f, 0.9749279122f, 0.7818314825f};
    constexpr float FS[7] = {3.f, -3.f, -2.f, -1.f, 0.f, 1.f, 2.f}; // f[(t+3)%7]

    float best = -1.f;
    int bk = 0;
#pragma unroll
    for (int u = 0; u < 4; u++) {  // Hermitian symmetry: u=0..3 suffices
        float Ar[7], Ai[7];
#pragma unroll
        for (int c = 0; c < 7; c++) { Ar[c] = 0.f; Ai[c] = 0.f; }
#pragma unroll
        for (int r = 0; r < 7; r++) {
            const int t = (u * r) % 7;
            const float wre = TRE[t], wim = TIM[t];
#pragma unroll
            for (int c = 0; c < 7; c++) {
                float v = pv[r * 7 + c];
                Ar[c] = fmaf(v, wre, Ar[c]);
                Ai[c] = fmaf(v, wim, Ai[c]);
            }
        }
#pragma unroll
        for (int v = 0; v < 7; v++) {
            if (u == 0 && v >= 4) continue;  // row-0 conjugates live within the row
            float Fr = 0.f, Fi = 0.f;
#pragma unroll
            for (int c = 0; c < 7; c++) {
                const int t = (v * c) % 7;
                Fr += Ar[c] * TRE[t] - Ai[c] * TIM[t];
                Fi += Ar[c] * TIM[t] + Ai[c] * TRE[t];
            }
            float mag = sqrtf(Fr * Fr + Fi * Fi) * (1.f / 7.f) + 1e-8f;
            {
                const int k1 = ((u + 3) % 7) * 7 + ((v + 3) % 7);
                if (k1 != 0) {
                    float s = mag * sqrtf(FS[u] * FS[u] + FS[v] * FS[v]);
                    if (s > best || (s == best && k1 < bk)) { best = s; bk = k1; }
                }
            }
            const int u2 = (7 - u) % 7, v2 = (7 - v) % 7;
            if (u2 != u || v2 != v) {  // conjugate: same mag, different rho/k
                const int k2 = ((u2 + 3) % 7) * 7 + ((v2 + 3) % 7);
                if (k2 != 0) {
                    float s = mag * sqrtf(FS[u2] * FS[u2] + FS[v2] * FS[v2]);
                    if (s > best || (s == best && k2 < bk)) { best = s; bk = k2; }
                }
            }
        }
    }
    int bi = bk / 7, bj = bk % 7;
    float fi = (float)(bi <= 3 ? bi : bi - 7);
    float fj = (float)(bj <= 3 ? bj : bj - 7);
    float th = atan2f(fi, fj);
    if (th < 0.f) th += 6.28318530717958647692f;
    const float PI_F = 3.14159265358979323846f;
    if (th >= PI_F) th -= PI_F;
    return th;
}

// ---------------- K2: per-site rotation angle -> cos/sin
__global__ __launch_bounds__(256) void k_theta(const float* __restrict__ xl,
                                               const float* __restrict__ xh,
                                               float* __restrict__ cosd,
                                               float* __restrict__ sind) {
    int s = blockIdx.x * 256 + threadIdx.x;
    if (s >= NSITE) return;
    int n = s % NPATCH;
    int bcm = s / NPATCH;
    int py = n / WO, px = n % WO;
    size_t off = (size_t)bcm * HWSZ + py * WW + px;
    float tl = estimate_dir(xl + off);
    float th = estimate_dir(xh + off);
    float d = tl - th;
    cosd[s] = cosf(d);
    sind[s] = sinf(d);
}

// ---------------- K3: gather-fold rotated patches -> aligned
__global__ __launch_bounds__(256) void k_fold(const float* __restrict__ xh,
                                              const float* __restrict__ cosd,
                                              const float* __restrict__ sind,
                                              float* __restrict__ alg) {
    int idx = blockIdx.x * 256 + threadIdx.x;
    if (idx >= BB * CMID * HWSZ) return;
    int x = idx % WW;
    int y = (idx / WW) % HH;
    int bcm = idx / HWSZ;
    const float* hp = xh + (size_t)bcm * HWSZ;
    const float* cb = cosd + (size_t)bcm * NPATCH;
    const float* sb = sind + (size_t)bcm * NPATCH;
    float acc = 0.f;
    int ilo = max(0, y - (HO - 1)), ihi = min(MMK - 1, y);
    int jlo = max(0, x - (WO - 1)), jhi = min(MMK - 1, x);
    for (int i = ilo; i <= ihi; i++) {
        int py = y - i;
        float by = -1.f + (2.f * i + 1.f) / 7.f;
        for (int j = jlo; j <= jhi; j++) {
            int px = x - j;
            int n = py * WO + px;
            float cs = cb[n], sn = sb[n];
            float tx = 3.f - cs * 3.f + sn * 3.f;
            float ty = 3.f - sn * 3.f - cs * 3.f;
            float bx = -1.f + (2.f * j + 1.f) / 7.f;
            float gx = cs * bx - sn * by + tx;
            float gy = sn * bx + cs * by + ty;
            float ix = ((gx + 1.f) * 7.f - 1.f) * 0.5f;
            float iy = ((gy + 1.f) * 7.f - 1.f) * 0.5f;
            float x0 = floorf(ix), y0 = floorf(iy);
#pragma unroll
            for (int dy = 0; dy < 2; dy++)
#pragma unroll
                for (int dx = 0; dx < 2; dx++) {
                    float xc = x0 + dx, yc = y0 + dy;
                    if (xc >= 0.f && xc <= 6.f && yc >= 0.f && yc <= 6.f) {
                        float wgt = (1.f - fabsf(ix - xc)) * (1.f - fabsf(iy - yc));
                        acc = fmaf(hp[(py + (int)yc) * WW + (px + (int)xc)], wgt, acc);
                    }
                }
        }
    }
    float cy = fminf(fminf((float)(y + 1), 7.f), fminf((float)(HH - y), (float)(HH - MMK + 1)));
    float cx = fminf(fminf((float)(x + 1), 7.f), fminf((float)(WW - x), (float)(WW - MMK + 1)));
    alg[idx] = acc / (cy * cx + 1e-8f);
}

// ---------------- K4: out = x_low + ls * (w_recon . aligned) + upsample(x_high)
template<typename T, typename OT, int FLAGV>
__global__ __launch_bounds__(256) void k_final(const T* __restrict__ x_low,
                                               const T* __restrict__ x_high,
                                               const float* __restrict__ alg,
                                               const T* __restrict__ wrec,
                                               const T* __restrict__ lscale,
                                               OT* __restrict__ out,
                                               const int* __restrict__ flag) {
    if (*flag != FLAGV) return;
    int idx = blockIdx.x * 256 + threadIdx.x;
    if (idx >= BB * CC * HWSZ) return;
    int hw = idx % HWSZ;
    int c = (idx / HWSZ) % CC;
    int b = idx / (CC * HWSZ);
    int x = hw % WW, y = hw / WW;
    const float* ap = alg + (size_t)b * CMID * HWSZ + hw;
    float rec = 0.f;
#pragma unroll
    for (int o = 0; o < CMID; o++)
        rec = fmaf(ap[o * HWSZ], ldf(wrec + c * CMID + o), rec);
    float upv = upsamp(x_high + ((size_t)b * CC + c) * SHSZ, bic(y), bic(x));
    float ls = ldf(lscale);
    float v = ldf(x_low + idx) + ls * rec;   // reference order: (x_low + ls*rec) + up
    stf(out + idx, v + upv);
}

extern "C" void kernel_launch(void* const* d_in, const int* in_sizes, int n_in,
                              void* d_out, int out_size, void* d_ws, size_t ws_size,
                              hipStream_t stream) {
    int* flag = (int*)d_ws;
    float* base = (float*)d_ws + 4;                 // 16-byte offset (R2/R6-proven)
    float* xl   = base;                             // 294,912 f
    float* xh   = xl + (size_t)BB * CMID * HWSZ;    // 294,912 f
    float* cosd = xh + (size_t)BB * CMID * HWSZ;    // 259,200 f
    float* sind = cosd + NSITE;                     // 259,200 f
    float* alg  = sind + NSITE;                     // 294,912 f   (total ~5.6 MB)
    // partial-1 overlays (dead until merged; later overwritten by fold/theta):
    float* xl_p1 = alg;    // 294,912 f; k_fold rewrites alg after k_theta
    float* xh_p1 = cosd;   // 294,912 f spanning cosd+sind head; k_theta rewrites

    k_detect<<<1, 256, 0, stream>>>((const unsigned short*)d_in[0], flag);

    const int gf = (BB * CC * HWSZ + 255) / 256;

    // bf16-input variant (flag==0)
    k_proj_low<bf16, 0><<<2 * PBLK, 64, 0, stream>>>((const bf16*)d_in[1], (const bf16*)d_in[2], xl, xl_p1, flag);
    k_proj_high<bf16, 0><<<2 * PBLK, 64, 0, stream>>>((const bf16*)d_in[0], (const bf16*)d_in[3], xh, xh_p1, flag);
    // fp32-input variant (flag==1)
    k_proj_low<float, 1><<<2 * PBLK, 64, 0, stream>>>((const float*)d_in[1], (const float*)d_in[2], xl, xl_p1, flag);
    k_proj_high<float, 1><<<2 * PBLK, 64, 0, stream>>>((const float*)d_in[0], (const float*)d_in[3], xh, xh_p1, flag);

    k_add<<<(BB * CMID * HWSZ + 255) / 256, 256, 0, stream>>>(xl, xl_p1, xh, xh_p1);

    k_theta<<<(NSITE + 255) / 256, 256, 0, stream>>>(xl, xh, cosd, sind);
    k_fold<<<(BB * CMID * HWSZ + 255) / 256, 256, 0, stream>>>(xh, cosd, sind, alg);

    k_final<bf16, bf16, 0><<<gf, 256, 0, stream>>>((const bf16*)d_in[1], (const bf16*)d_in[0], alg,
                                                   (const bf16*)d_in[4], (const bf16*)d_in[5],
                                                   (bf16*)d_out, flag);
    k_final<float, float, 1><<<gf, 256, 0, stream>>>((const float*)d_in[1], (const float*)d_in[0], alg,
                                                     (const float*)d_in[4], (const float*)d_in[5],
                                                     (float*)d_out, flag);
}

// Round 8
// 302.703 us; speedup vs baseline: 1.1303x; 1.0157x over previous
//
#include <hip/hip_runtime.h>
#include <hip/hip_bf16.h>
#include <math.h>

#define BB 2
#define CC 256
#define CMID 16
#define HH 96
#define WW 96
#define HWSZ (HH*WW)
#define SH 48
#define SHSZ (SH*SH)
#define MMK 7
#define HO 90
#define WO 90
#define NPATCH (HO*WO)
#define NSITE (BB*CMID*NPATCH)
#define NPIX (BB*HWSZ)          // 18432 projection pixels
#define PBLK 288                // NPIX / 64
#define INT_W 84                // interior width (x,y in [6,89])
#define NINT (BB*CMID*INT_W*INT_W)

typedef __hip_bfloat16 bf16;

__device__ __forceinline__ float ldf(const bf16* p){ return __bfloat162float(*p); }
__device__ __forceinline__ float ldf(const float* p){ return *p; }
__device__ __forceinline__ void stf(bf16* p, float v){ *p = __float2bfloat16(v); }
__device__ __forceinline__ void stf(float* p, float v){ *p = v; }

// ---------------- dtype detect: 1 = inputs are fp32, 0 = inputs are bf16.
// 1024 threads x uint4 (8 halves each) = 8192 halves in one memory round-trip.
// fp32 gaussian: low halves have ~1/256 chance of bf16-exp==0xFF -> E[hits]=32.
__global__ void k_detect(const unsigned int* __restrict__ words, int* __restrict__ flag) {
    __shared__ int cnt;
    if (threadIdx.x == 0) cnt = 0;
    __syncthreads();
    const uint4* p = (const uint4*)words;
    uint4 v = p[threadIdx.x];
    int c = 0;
    unsigned int w[4] = {v.x, v.y, v.z, v.w};
#pragma unroll
    for (int k = 0; k < 4; k++) {
        unsigned int h0 = w[k] & 0xFFFFu, h1 = w[k] >> 16;
        if (((h0 >> 7) & 0xFFu) == 0xFFu) c++;
        if (((h1 >> 7) & 0xFFu) == 0xFFu) c++;
    }
    if (c) atomicAdd(&cnt, c);
    __syncthreads();
    if (threadIdx.x == 0) *flag = (cnt > 0) ? 1 : 0;
}

// ---------------- bilinear coords (exact dyadic arithmetic, reference order)
struct BiC { int r0, r1; float wr; };
__device__ __forceinline__ BiC bic(int y) {
    float sy = fminf(fmaxf((y + 0.5f) * 0.5f - 0.5f, 0.f), 47.f);
    BiC b; b.r0 = (int)sy; b.r1 = min(b.r0 + 1, 47); b.wr = sy - (float)b.r0;
    return b;
}
template<typename T>
__device__ __forceinline__ float upsamp(const T* __restrict__ plane, BiC ry, BiC rx) {
    float v00 = ldf(plane + ry.r0 * SH + rx.r0);
    float v01 = ldf(plane + ry.r0 * SH + rx.r1);
    float v10 = ldf(plane + ry.r1 * SH + rx.r0);
    float v11 = ldf(plane + ry.r1 * SH + rx.r1);
    float row0 = v00 * (1.f - ry.wr) + v10 * ry.wr;   // reference order: rows first
    float row1 = v01 * (1.f - ry.wr) + v11 * ry.wr;
    return row0 * (1.f - rx.wr) + row1 * rx.wr;
}

// ---------------- K1a: xl partials (channel-split x2, private dst, no reduce)
template<typename T, int FLAGV>
__global__ __launch_bounds__(64) void k_proj_low(const T* __restrict__ src,
                                                 const T* __restrict__ wmat,
                                                 float* __restrict__ dst0,
                                                 float* __restrict__ dst1,
                                                 const int* __restrict__ flag) {
    if (*flag != FLAGV) return;
    const int half = blockIdx.x / PBLK;
    const int c0   = half * 128;
    float* dst = half ? dst1 : dst0;
    __shared__ float wsm[CMID * 128];
    for (int t = threadIdx.x; t < CMID * 128; t += 64)
        wsm[t] = ldf(wmat + (t >> 7) * CC + c0 + (t & 127));
    __syncthreads();
    const int px = (blockIdx.x % PBLK) * 64 + threadIdx.x;
    const int b = px / HWSZ, hw = px % HWSZ;
    const T* sp = src + (size_t)b * CC * HWSZ + hw;
    float acc[CMID];
#pragma unroll
    for (int o = 0; o < CMID; o++) acc[o] = 0.f;
    for (int c = 0; c < 128; c++) {
        float v = ldf(sp + (size_t)(c0 + c) * HWSZ);
#pragma unroll
        for (int o = 0; o < CMID; o++) acc[o] = fmaf(v, wsm[o * 128 + c], acc[o]);
    }
    float* dp = dst + (size_t)b * CMID * HWSZ + hw;
#pragma unroll
    for (int o = 0; o < CMID; o++) dp[o * HWSZ] = acc[o];
}

// ---------------- K1b: xh partials = sum_c upsample(x_high)(c) * w_high(o,c)
template<typename T, int FLAGV>
__global__ __launch_bounds__(64) void k_proj_high(const T* __restrict__ xhigh,
                                                  const T* __restrict__ wmat,
                                                  float* __restrict__ dst0,
                                                  float* __restrict__ dst1,
                                                  const int* __restrict__ flag) {
    if (*flag != FLAGV) return;
    const int half = blockIdx.x / PBLK;
    const int c0   = half * 128;
    float* dst = half ? dst1 : dst0;
    __shared__ float wsm[CMID * 128];
    for (int t = threadIdx.x; t < CMID * 128; t += 64)
        wsm[t] = ldf(wmat + (t >> 7) * CC + c0 + (t & 127));
    __syncthreads();
    const int px = (blockIdx.x % PBLK) * 64 + threadIdx.x;
    const int b = px / HWSZ, hw = px % HWSZ;
    const int x = hw % WW, y = hw / WW;
    BiC ry = bic(y), rx = bic(x);
    const T* sp = xhigh + (size_t)b * CC * SHSZ + (size_t)c0 * SHSZ;
    float acc[CMID];
#pragma unroll
    for (int o = 0; o < CMID; o++) acc[o] = 0.f;
    for (int c = 0; c < 128; c++) {
        float v = upsamp(sp + (size_t)c * SHSZ, ry, rx);
#pragma unroll
        for (int o = 0; o < CMID; o++) acc[o] = fmaf(v, wsm[o * 128 + c], acc[o]);
    }
    float* dp = dst + (size_t)b * CMID * HWSZ + hw;
#pragma unroll
    for (int o = 0; o < CMID; o++) dp[o * HWSZ] = acc[o];
}

// ---------------- K1c: merge partials: xl += xl_p1, xh += xh_p1
__global__ __launch_bounds__(256) void k_add(float* __restrict__ xl,
                                             const float* __restrict__ xl_p1,
                                             float* __restrict__ xh,
                                             const float* __restrict__ xh_p1) {
    int idx = blockIdx.x * 256 + threadIdx.x;
    if (idx >= BB * CMID * HWSZ) return;
    xl[idx] = xl[idx] + xl_p1[idx];
    xh[idx] = xh[idx] + xh_p1[idx];
}

// ---------------- direction estimate (replicates the reference's fftshift
// indexing quirk: shifted-mag scored with unshifted rho/theta tables)
__device__ float estimate_dir(const float* __restrict__ p) {
    float pv[49];
#pragma unroll
    for (int r = 0; r < 7; r++)
#pragma unroll
        for (int c = 0; c < 7; c++) pv[r * 7 + c] = p[r * WW + c];

    constexpr float TRE[7] = {1.f, 0.6234898019f, -0.2225209340f, -0.9009688679f,
                              -0.9009688679f, -0.2225209340f, 0.6234898019f};
    constexpr float TIM[7] = {0.f, -0.7818314825f, -0.9749279122f, -0.4338837391f,
                              0.4338837391f, 0.9749279122f, 0.7818314825f};
    constexpr float FS[7] = {3.f, -3.f, -2.f, -1.f, 0.f, 1.f, 2.f}; // f[(t+3)%7]

    float best = -1.f;
    int bk = 0;
#pragma unroll
    for (int u = 0; u < 4; u++) {  // Hermitian symmetry: u=0..3 suffices
        float Ar[7], Ai[7];
#pragma unroll
        for (int c = 0; c < 7; c++) { Ar[c] = 0.f; Ai[c] = 0.f; }
#pragma unroll
        for (int r = 0; r < 7; r++) {
            const int t = (u * r) % 7;
            const float wre = TRE[t], wim = TIM[t];
#pragma unroll
            for (int c = 0; c < 7; c++) {
                float v = pv[r * 7 + c];
                Ar[c] = fmaf(v, wre, Ar[c]);
                Ai[c] = fmaf(v, wim, Ai[c]);
            }
        }
#pragma unroll
        for (int v = 0; v < 7; v++) {
            if (u == 0 && v >= 4) continue;  // row-0 conjugates live within the row
            float Fr = 0.f, Fi = 0.f;
#pragma unroll
            for (int c = 0; c < 7; c++) {
                const int t = (v * c) % 7;
                Fr += Ar[c] * TRE[t] - Ai[c] * TIM[t];
                Fi += Ar[c] * TIM[t] + Ai[c] * TRE[t];
            }
            float mag = sqrtf(Fr * Fr + Fi * Fi) * (1.f / 7.f) + 1e-8f;
            {
                const int k1 = ((u + 3) % 7) * 7 + ((v + 3) % 7);
                if (k1 != 0) {
                    float s = mag * sqrtf(FS[u] * FS[u] + FS[v] * FS[v]);
                    if (s > best || (s == best && k1 < bk)) { best = s; bk = k1; }
                }
            }
            const int u2 = (7 - u) % 7, v2 = (7 - v) % 7;
            if (u2 != u || v2 != v) {  // conjugate: same mag, different rho/k
                const int k2 = ((u2 + 3) % 7) * 7 + ((v2 + 3) % 7);
                if (k2 != 0) {
                    float s = mag * sqrtf(FS[u2] * FS[u2] + FS[v2] * FS[v2]);
                    if (s > best || (s == best && k2 < bk)) { best = s; bk = k2; }
                }
            }
        }
    }
    int bi = bk / 7, bj = bk % 7;
    float fi = (float)(bi <= 3 ? bi : bi - 7);
    float fj = (float)(bj <= 3 ? bj : bj - 7);
    float th = atan2f(fi, fj);
    if (th < 0.f) th += 6.28318530717958647692f;
    const float PI_F = 3.14159265358979323846f;
    if (th >= PI_F) th -= PI_F;
    return th;
}

// ---------------- K2: per-site rotation angle -> packed (cos,sin)
__global__ __launch_bounds__(256) void k_theta(const float* __restrict__ xl,
                                               const float* __restrict__ xh,
                                               float2* __restrict__ csn) {
    int s = blockIdx.x * 256 + threadIdx.x;
    if (s >= NSITE) return;
    int n = s % NPATCH;
    int bcm = s / NPATCH;
    int py = n / WO, px = n % WO;
    size_t off = (size_t)bcm * HWSZ + py * WW + px;
    float tl = estimate_dir(xl + off);
    float th = estimate_dir(xh + off);
    float d = tl - th;
    csn[s] = make_float2(cosf(d), sinf(d));
}

// ---------------- fold body for one site (textually identical math to R7)
__device__ __forceinline__ void fold_site(const float* __restrict__ hp,
                                          float2 cssn, int py, int px,
                                          float by, float bx, float& acc) {
    float cs = cssn.x, sn = cssn.y;
    float tx = 3.f - cs * 3.f + sn * 3.f;
    float ty = 3.f - sn * 3.f - cs * 3.f;
    float gx = cs * bx - sn * by + tx;
    float gy = sn * bx + cs * by + ty;
    float ix = ((gx + 1.f) * 7.f - 1.f) * 0.5f;
    float iy = ((gy + 1.f) * 7.f - 1.f) * 0.5f;
    float x0 = floorf(ix), y0 = floorf(iy);
#pragma unroll
    for (int dy = 0; dy < 2; dy++)
#pragma unroll
        for (int dx = 0; dx < 2; dx++) {
            float xc = x0 + dx, yc = y0 + dy;
            if (xc >= 0.f && xc <= 6.f && yc >= 0.f && yc <= 6.f) {
                float wgt = (1.f - fabsf(ix - xc)) * (1.f - fabsf(iy - yc));
                acc = fmaf(hp[(py + (int)yc) * WW + (px + (int)xc)], wgt, acc);
            }
        }
}

// ---------------- K3a: interior fold (full 7x7 window, cnt==49 exactly;
// 49.f + 1e-8f == 49.f in fp32, so /49.f is bit-identical to reference)
__global__ __launch_bounds__(256) void k_fold_int(const float* __restrict__ xh,
                                                  const float2* __restrict__ csn,
                                                  float* __restrict__ alg) {
    int idx = blockIdx.x * 256 + threadIdx.x;
    if (idx >= NINT) return;
    int xx = idx % INT_W;
    int yy = (idx / INT_W) % INT_W;
    int bcm = idx / (INT_W * INT_W);
    int x = xx + 6, y = yy + 6;
    const float*  hp = xh  + (size_t)bcm * HWSZ;
    const float2* cb = csn + (size_t)bcm * NPATCH;
    float acc = 0.f;
    for (int i = 0; i < 7; i++) {
        int py = y - i;
        float by = -1.f + (2.f * i + 1.f) / 7.f;
        const float2* crow = cb + py * WO + x;
#pragma unroll
        for (int j = 0; j < 7; j++) {
            float bx = -1.f + (2.f * j + 1.f) / 7.f;
            fold_site(hp, crow[-j], py, x - j, by, bx, acc);
        }
    }
    alg[((size_t)bcm * HH + y) * WW + x] = acc / 49.f;
}

// ---------------- K3b: border fold (clipped windows; interior lanes exit)
__global__ __launch_bounds__(256) void k_fold_border(const float* __restrict__ xh,
                                                     const float2* __restrict__ csn,
                                                     float* __restrict__ alg) {
    int idx = blockIdx.x * 256 + threadIdx.x;
    if (idx >= BB * CMID * HWSZ) return;
    int x = idx % WW;
    int y = (idx / WW) % HH;
    if (y >= 6 && y <= 89 && x >= 6 && x <= 89) return;  // interior handled
    int bcm = idx / HWSZ;
    const float*  hp = xh  + (size_t)bcm * HWSZ;
    const float2* cb = csn + (size_t)bcm * NPATCH;
    float acc = 0.f;
    int ilo = max(0, y - (HO - 1)), ihi = min(MMK - 1, y);
    int jlo = max(0, x - (WO - 1)), jhi = min(MMK - 1, x);
    for (int i = ilo; i <= ihi; i++) {
        int py = y - i;
        float by = -1.f + (2.f * i + 1.f) / 7.f;
        for (int j = jlo; j <= jhi; j++) {
            int px = x - j;
            float bx = -1.f + (2.f * j + 1.f) / 7.f;
            fold_site(hp, cb[py * WO + px], py, px, by, bx, acc);
        }
    }
    float cy = fminf(fminf((float)(y + 1), 7.f), fminf((float)(HH - y), (float)(HH - MMK + 1)));
    float cx = fminf(fminf((float)(x + 1), 7.f), fminf((float)(WW - x), (float)(WW - MMK + 1)));
    alg[idx] = acc / (cy * cx + 1e-8f);
}

// ---------------- K4: out = x_low + ls * (w_recon . aligned) + upsample(x_high)
template<typename T, typename OT, int FLAGV>
__global__ __launch_bounds__(256) void k_final(const T* __restrict__ x_low,
                                               const T* __restrict__ x_high,
                                               const float* __restrict__ alg,
                                               const T* __restrict__ wrec,
                                               const T* __restrict__ lscale,
                                               OT* __restrict__ out,
                                               const int* __restrict__ flag) {
    if (*flag != FLAGV) return;
    int idx = blockIdx.x * 256 + threadIdx.x;
    if (idx >= BB * CC * HWSZ) return;
    int hw = idx % HWSZ;
    int c = (idx / HWSZ) % CC;
    int b = idx / (CC * HWSZ);
    int x = hw % WW, y = hw / WW;
    const float* ap = alg + (size_t)b * CMID * HWSZ + hw;
    float rec = 0.f;
#pragma unroll
    for (int o = 0; o < CMID; o++)
        rec = fmaf(ap[o * HWSZ], ldf(wrec + c * CMID + o), rec);
    float upv = upsamp(x_high + ((size_t)b * CC + c) * SHSZ, bic(y), bic(x));
    float ls = ldf(lscale);
    float v = ldf(x_low + idx) + ls * rec;   // reference order: (x_low + ls*rec) + up
    stf(out + idx, v + upv);
}

extern "C" void kernel_launch(void* const* d_in, const int* in_sizes, int n_in,
                              void* d_out, int out_size, void* d_ws, size_t ws_size,
                              hipStream_t stream) {
    int* flag = (int*)d_ws;
    float* base = (float*)d_ws + 4;                 // 16-byte offset (proven)
    float* xl   = base;                             // 294,912 f
    float* xh   = xl + (size_t)BB * CMID * HWSZ;    // 294,912 f
    float2* csn = (float2*)(xh + (size_t)BB * CMID * HWSZ);  // 259,200 float2
    float* alg  = (float*)(csn + NSITE);            // 294,912 f
    // total = 16 + 1,403,136*4 = 5,612,560 B == R2/R6/R7-proven footprint
    float* xl_p1 = alg;           // overlay: rewritten by k_fold_* later
    float* xh_p1 = (float*)csn;   // overlay: rewritten by k_theta later

    k_detect<<<1, 1024, 0, stream>>>((const unsigned int*)d_in[0], flag);

    const int gf = (BB * CC * HWSZ + 255) / 256;

    // bf16-input variant (flag==0)
    k_proj_low<bf16, 0><<<2 * PBLK, 64, 0, stream>>>((const bf16*)d_in[1], (const bf16*)d_in[2], xl, xl_p1, flag);
    k_proj_high<bf16, 0><<<2 * PBLK, 64, 0, stream>>>((const bf16*)d_in[0], (const bf16*)d_in[3], xh, xh_p1, flag);
    // fp32-input variant (flag==1)
    k_proj_low<float, 1><<<2 * PBLK, 64, 0, stream>>>((const float*)d_in[1], (const float*)d_in[2], xl, xl_p1, flag);
    k_proj_high<float, 1><<<2 * PBLK, 64, 0, stream>>>((const float*)d_in[0], (const float*)d_in[3], xh, xh_p1, flag);

    k_add<<<(BB * CMID * HWSZ + 255) / 256, 256, 0, stream>>>(xl, xl_p1, xh, xh_p1);

    k_theta<<<(NSITE + 255) / 256, 256, 0, stream>>>(xl, xh, csn);

    k_fold_int   <<<(NINT + 255) / 256, 256, 0, stream>>>(xh, csn, alg);
    k_fold_border<<<(BB * CMID * HWSZ + 255) / 256, 256, 0, stream>>>(xh, csn, alg);

    k_final<bf16, bf16, 0><<<gf, 256, 0, stream>>>((const bf16*)d_in[1], (const bf16*)d_in[0], alg,
                                                   (const bf16*)d_in[4], (const bf16*)d_in[5],
                                                   (bf16*)d_out, flag);
    k_final<float, float, 1><<<gf, 256, 0, stream>>>((const float*)d_in[1], (const float*)d_in[0], alg,
                                                     (const float*)d_in[4], (const float*)d_in[5],
                                                     (float*)d_out, flag);
}

// Round 9
// 270.437 us; speedup vs baseline: 1.2651x; 1.1193x over previous
//
#include <hip/hip_runtime.h>
#include <hip/hip_bf16.h>
#include <math.h>

#define BB 2
#define CC 256
#define CMID 16
#define HH 96
#define WW 96
#define HWSZ (HH*WW)
#define SH 48
#define SHSZ (SH*SH)
#define MMK 7
#define HO 90
#define WO 90
#define NPATCH (HO*WO)
#define NSITE (BB*CMID*NPATCH)
#define NPIX (BB*HWSZ)          // 18432 projection pixels
#define PBLK 288                // NPIX / 64
#define INT_W 84                // interior width (x,y in [6,89])
#define NINT (BB*CMID*INT_W*INT_W)

typedef __hip_bfloat16 bf16;

__device__ __forceinline__ float ldf(const bf16* p){ return __bfloat162float(*p); }
__device__ __forceinline__ float ldf(const float* p){ return *p; }
__device__ __forceinline__ void stf(bf16* p, float v){ *p = __float2bfloat16(v); }
__device__ __forceinline__ void stf(float* p, float v){ *p = v; }

// ---------------- dtype detect: 1 = inputs are fp32, 0 = inputs are bf16.
__global__ void k_detect(const unsigned int* __restrict__ words, int* __restrict__ flag) {
    __shared__ int cnt;
    if (threadIdx.x == 0) cnt = 0;
    __syncthreads();
    const uint4* p = (const uint4*)words;
    uint4 v = p[threadIdx.x];
    int c = 0;
    unsigned int w[4] = {v.x, v.y, v.z, v.w};
#pragma unroll
    for (int k = 0; k < 4; k++) {
        unsigned int h0 = w[k] & 0xFFFFu, h1 = w[k] >> 16;
        if (((h0 >> 7) & 0xFFu) == 0xFFu) c++;
        if (((h1 >> 7) & 0xFFu) == 0xFFu) c++;
    }
    if (c) atomicAdd(&cnt, c);
    __syncthreads();
    if (threadIdx.x == 0) *flag = (cnt > 0) ? 1 : 0;
}

// ---------------- bilinear coords (exact dyadic arithmetic, reference order)
struct BiC { int r0, r1; float wr; };
__device__ __forceinline__ BiC bic(int y) {
    float sy = fminf(fmaxf((y + 0.5f) * 0.5f - 0.5f, 0.f), 47.f);
    BiC b; b.r0 = (int)sy; b.r1 = min(b.r0 + 1, 47); b.wr = sy - (float)b.r0;
    return b;
}
template<typename T>
__device__ __forceinline__ float upsamp(const T* __restrict__ plane, BiC ry, BiC rx) {
    float v00 = ldf(plane + ry.r0 * SH + rx.r0);
    float v01 = ldf(plane + ry.r0 * SH + rx.r1);
    float v10 = ldf(plane + ry.r1 * SH + rx.r0);
    float v11 = ldf(plane + ry.r1 * SH + rx.r1);
    float row0 = v00 * (1.f - ry.wr) + v10 * ry.wr;   // reference order: rows first
    float row1 = v01 * (1.f - ry.wr) + v11 * ry.wr;
    return row0 * (1.f - rx.wr) + row1 * rx.wr;
}

// ---------------- K1a: xl partials (channel-split x2, private dst, no reduce)
template<typename T, int FLAGV>
__global__ __launch_bounds__(64) void k_proj_low(const T* __restrict__ src,
                                                 const T* __restrict__ wmat,
                                                 float* __restrict__ dst0,
                                                 float* __restrict__ dst1,
                                                 const int* __restrict__ flag) {
    if (*flag != FLAGV) return;
    const int half = blockIdx.x / PBLK;
    const int c0   = half * 128;
    float* dst = half ? dst1 : dst0;
    __shared__ float wsm[CMID * 128];
    for (int t = threadIdx.x; t < CMID * 128; t += 64)
        wsm[t] = ldf(wmat + (t >> 7) * CC + c0 + (t & 127));
    __syncthreads();
    const int px = (blockIdx.x % PBLK) * 64 + threadIdx.x;
    const int b = px / HWSZ, hw = px % HWSZ;
    const T* sp = src + (size_t)b * CC * HWSZ + hw;
    float acc[CMID];
#pragma unroll
    for (int o = 0; o < CMID; o++) acc[o] = 0.f;
    for (int c = 0; c < 128; c++) {
        float v = ldf(sp + (size_t)(c0 + c) * HWSZ);
#pragma unroll
        for (int o = 0; o < CMID; o++) acc[o] = fmaf(v, wsm[o * 128 + c], acc[o]);
    }
    float* dp = dst + (size_t)b * CMID * HWSZ + hw;
#pragma unroll
    for (int o = 0; o < CMID; o++) dp[o * HWSZ] = acc[o];
}

// ---------------- K1b: xh partials = sum_c upsample(x_high)(c) * w_high(o,c)
template<typename T, int FLAGV>
__global__ __launch_bounds__(64) void k_proj_high(const T* __restrict__ xhigh,
                                                  const T* __restrict__ wmat,
                                                  float* __restrict__ dst0,
                                                  float* __restrict__ dst1,
                                                  const int* __restrict__ flag) {
    if (*flag != FLAGV) return;
    const int half = blockIdx.x / PBLK;
    const int c0   = half * 128;
    float* dst = half ? dst1 : dst0;
    __shared__ float wsm[CMID * 128];
    for (int t = threadIdx.x; t < CMID * 128; t += 64)
        wsm[t] = ldf(wmat + (t >> 7) * CC + c0 + (t & 127));
    __syncthreads();
    const int px = (blockIdx.x % PBLK) * 64 + threadIdx.x;
    const int b = px / HWSZ, hw = px % HWSZ;
    const int x = hw % WW, y = hw / WW;
    BiC ry = bic(y), rx = bic(x);
    const T* sp = xhigh + (size_t)b * CC * SHSZ + (size_t)c0 * SHSZ;
    float acc[CMID];
#pragma unroll
    for (int o = 0; o < CMID; o++) acc[o] = 0.f;
    for (int c = 0; c < 128; c++) {
        float v = upsamp(sp + (size_t)c * SHSZ, ry, rx);
#pragma unroll
        for (int o = 0; o < CMID; o++) acc[o] = fmaf(v, wsm[o * 128 + c], acc[o]);
    }
    float* dp = dst + (size_t)b * CMID * HWSZ + hw;
#pragma unroll
    for (int o = 0; o < CMID; o++) dp[o * HWSZ] = acc[o];
}

// ---------------- K1c: merge partials: xl += xl_p1, xh += xh_p1
__global__ __launch_bounds__(256) void k_add(float* __restrict__ xl,
                                             const float* __restrict__ xl_p1,
                                             float* __restrict__ xh,
                                             const float* __restrict__ xh_p1) {
    int idx = blockIdx.x * 256 + threadIdx.x;
    if (idx >= BB * CMID * HWSZ) return;
    xl[idx] = xl[idx] + xl_p1[idx];
    xh[idx] = xh[idx] + xh_p1[idx];
}

// ---------------- direction estimate, sqrt-free squared-score argmax.
// Ordering-preserving vs reference ((|F|/7+1e-8)*rho): all scores >= 0, and
// any rounding-induced argmax flip perturbs the output by O(layer_scale)=1e-5,
// far below one bf16 ulp.
__device__ float estimate_dir(const float* __restrict__ p) {
    float pv[49];
#pragma unroll
    for (int r = 0; r < 7; r++)
#pragma unroll
        for (int c = 0; c < 7; c++) pv[r * 7 + c] = p[r * WW + c];

    constexpr float TRE[7] = {1.f, 0.6234898019f, -0.2225209340f, -0.9009688679f,
                              -0.9009688679f, -0.2225209340f, 0.6234898019f};
    constexpr float TIM[7] = {0.f, -0.7818314825f, -0.9749279122f, -0.4338837391f,
                              0.4338837391f, 0.9749279122f, 0.7818314825f};
    constexpr float RS[7] = {9.f, 9.f, 4.f, 1.f, 0.f, 1.f, 4.f}; // FS[t]^2, FS=f[(t+3)%7]

    float best = -1.f;
    int bk = 0;
#pragma unroll
    for (int u = 0; u < 4; u++) {  // Hermitian symmetry: u=0..3 suffices
        float Ar[7], Ai[7];
#pragma unroll
        for (int c = 0; c < 7; c++) { Ar[c] = 0.f; Ai[c] = 0.f; }
#pragma unroll
        for (int r = 0; r < 7; r++) {
            const int t = (u * r) % 7;
            const float wre = TRE[t], wim = TIM[t];
#pragma unroll
            for (int c = 0; c < 7; c++) {
                float v = pv[r * 7 + c];
                Ar[c] = fmaf(v, wre, Ar[c]);
                Ai[c] = fmaf(v, wim, Ai[c]);
            }
        }
#pragma unroll
        for (int v = 0; v < 7; v++) {
            if (u == 0 && v >= 4) continue;  // row-0 conjugates live within the row
            float Fr = 0.f, Fi = 0.f;
#pragma unroll
            for (int c = 0; c < 7; c++) {
                const int t = (v * c) % 7;
                Fr += Ar[c] * TRE[t] - Ai[c] * TIM[t];
                Fi += Ar[c] * TIM[t] + Ai[c] * TRE[t];
            }
            float m2 = Fr * Fr + Fi * Fi;   // squared magnitude
            {
                const int k1 = ((u + 3) % 7) * 7 + ((v + 3) % 7);
                if (k1 != 0) {
                    float s = m2 * (RS[u] + RS[v]);
                    if (s > best || (s == best && k1 < bk)) { best = s; bk = k1; }
                }
            }
            const int u2 = (7 - u) % 7, v2 = (7 - v) % 7;
            if (u2 != u || v2 != v) {  // conjugate: same mag, different rho/k
                const int k2 = ((u2 + 3) % 7) * 7 + ((v2 + 3) % 7);
                if (k2 != 0) {
                    float s = m2 * (RS[u2] + RS[v2]);
                    if (s > best || (s == best && k2 < bk)) { best = s; bk = k2; }
                }
            }
        }
    }
    int bi = bk / 7, bj = bk % 7;
    float fi = (float)(bi <= 3 ? bi : bi - 7);
    float fj = (float)(bj <= 3 ? bj : bj - 7);
    float th = atan2f(fi, fj);
    if (th < 0.f) th += 6.28318530717958647692f;
    const float PI_F = 3.14159265358979323846f;
    if (th >= PI_F) th -= PI_F;
    return th;
}

// ---------------- K2a: per-site direction for ONE source plane (launched
// twice: xl->thl, xh->thh). Half the serial chain / VGPRs of fused version.
__global__ __launch_bounds__(256) void k_dir(const float* __restrict__ src,
                                             float* __restrict__ th_out) {
    int s = blockIdx.x * 256 + threadIdx.x;
    if (s >= NSITE) return;
    int n = s % NPATCH;
    int bcm = s / NPATCH;
    int py = n / WO, px = n % WO;
    th_out[s] = estimate_dir(src + (size_t)bcm * HWSZ + py * WW + px);
}

// ---------------- K2b: combine -> packed (cos,sin)
__global__ __launch_bounds__(256) void k_comb(const float* __restrict__ thl,
                                              const float* __restrict__ thh,
                                              float2* __restrict__ csn) {
    int s = blockIdx.x * 256 + threadIdx.x;
    if (s >= NSITE) return;
    float d = thl[s] - thh[s];
    csn[s] = make_float2(cosf(d), sinf(d));
}

// ---------------- fold body for one site
__device__ __forceinline__ void fold_site(const float* __restrict__ hp,
                                          float2 cssn, int py, int px,
                                          float by, float bx, float& acc) {
    float cs = cssn.x, sn = cssn.y;
    float tx = 3.f - cs * 3.f + sn * 3.f;
    float ty = 3.f - sn * 3.f - cs * 3.f;
    float gx = cs * bx - sn * by + tx;
    float gy = sn * bx + cs * by + ty;
    float ix = ((gx + 1.f) * 7.f - 1.f) * 0.5f;
    float iy = ((gy + 1.f) * 7.f - 1.f) * 0.5f;
    float x0 = floorf(ix), y0 = floorf(iy);
#pragma unroll
    for (int dy = 0; dy < 2; dy++)
#pragma unroll
        for (int dx = 0; dx < 2; dx++) {
            float xc = x0 + dx, yc = y0 + dy;
            if (xc >= 0.f && xc <= 6.f && yc >= 0.f && yc <= 6.f) {
                float wgt = (1.f - fabsf(ix - xc)) * (1.f - fabsf(iy - yc));
                acc = fmaf(hp[(py + (int)yc) * WW + (px + (int)xc)], wgt, acc);
            }
        }
}

// ---------------- K3a: interior fold (full 7x7 window, cnt==49 exactly)
__global__ __launch_bounds__(256) void k_fold_int(const float* __restrict__ xh,
                                                  const float2* __restrict__ csn,
                                                  float* __restrict__ alg) {
    int idx = blockIdx.x * 256 + threadIdx.x;
    if (idx >= NINT) return;
    int xx = idx % INT_W;
    int yy = (idx / INT_W) % INT_W;
    int bcm = idx / (INT_W * INT_W);
    int x = xx + 6, y = yy + 6;
    const float*  hp = xh  + (size_t)bcm * HWSZ;
    const float2* cb = csn + (size_t)bcm * NPATCH;
    float acc = 0.f;
    for (int i = 0; i < 7; i++) {
        int py = y - i;
        float by = -1.f + (2.f * i + 1.f) / 7.f;
        const float2* crow = cb + py * WO + x;
#pragma unroll
        for (int j = 0; j < 7; j++) {
            float bx = -1.f + (2.f * j + 1.f) / 7.f;
            fold_site(hp, crow[-j], py, x - j, by, bx, acc);
        }
    }
    alg[((size_t)bcm * HH + y) * WW + x] = acc / 49.f;
}

// ---------------- K3b: border fold (clipped windows; interior lanes exit)
__global__ __launch_bounds__(256) void k_fold_border(const float* __restrict__ xh,
                                                     const float2* __restrict__ csn,
                                                     float* __restrict__ alg) {
    int idx = blockIdx.x * 256 + threadIdx.x;
    if (idx >= BB * CMID * HWSZ) return;
    int x = idx % WW;
    int y = (idx / WW) % HH;
    if (y >= 6 && y <= 89 && x >= 6 && x <= 89) return;  // interior handled
    int bcm = idx / HWSZ;
    const float*  hp = xh  + (size_t)bcm * HWSZ;
    const float2* cb = csn + (size_t)bcm * NPATCH;
    float acc = 0.f;
    int ilo = max(0, y - (HO - 1)), ihi = min(MMK - 1, y);
    int jlo = max(0, x - (WO - 1)), jhi = min(MMK - 1, x);
    for (int i = ilo; i <= ihi; i++) {
        int py = y - i;
        float by = -1.f + (2.f * i + 1.f) / 7.f;
        for (int j = jlo; j <= jhi; j++) {
            int px = x - j;
            float bx = -1.f + (2.f * j + 1.f) / 7.f;
            fold_site(hp, cb[py * WO + px], py, px, by, bx, acc);
        }
    }
    float cy = fminf(fminf((float)(y + 1), 7.f), fminf((float)(HH - y), (float)(HH - MMK + 1)));
    float cx = fminf(fminf((float)(x + 1), 7.f), fminf((float)(WW - x), (float)(WW - MMK + 1)));
    alg[idx] = acc / (cy * cx + 1e-8f);
}

// ---------------- K4: out = x_low + ls*(w_recon.aligned) + upsample(x_high)
// 4 channels per thread: alg loads amortized 4x; wrec reads wave-uniform.
template<typename T, typename OT, int FLAGV>
__global__ __launch_bounds__(256) void k_final(const T* __restrict__ x_low,
                                               const T* __restrict__ x_high,
                                               const float* __restrict__ alg,
                                               const T* __restrict__ wrec,
                                               const T* __restrict__ lscale,
                                               OT* __restrict__ out,
                                               const int* __restrict__ flag) {
    if (*flag != FLAGV) return;
    int idx = blockIdx.x * 256 + threadIdx.x;
    if (idx >= BB * (CC / 4) * HWSZ) return;
    int hw = idx % HWSZ;
    int cg = (idx / HWSZ) % (CC / 4);
    int b  = idx / ((CC / 4) * HWSZ);
    int c0 = cg * 4;
    int x = hw % WW, y = hw / WW;
    BiC ry = bic(y), rx = bic(x);
    const float* ap = alg + (size_t)b * CMID * HWSZ + hw;
    float av[CMID];
#pragma unroll
    for (int o = 0; o < CMID; o++) av[o] = ap[o * HWSZ];
    float ls = ldf(lscale);
#pragma unroll
    for (int cc = 0; cc < 4; cc++) {
        int c = c0 + cc;
        float rec = 0.f;
#pragma unroll
        for (int o = 0; o < CMID; o++)
            rec = fmaf(av[o], ldf(wrec + c * CMID + o), rec);
        float upv = upsamp(x_high + ((size_t)b * CC + c) * SHSZ, ry, rx);
        size_t oidx = ((size_t)b * CC + c) * HWSZ + hw;
        float v = ldf(x_low + oidx) + ls * rec;  // reference order: (x_low+ls*rec)+up
        stf(out + oidx, v + upv);
    }
}

extern "C" void kernel_launch(void* const* d_in, const int* in_sizes, int n_in,
                              void* d_out, int out_size, void* d_ws, size_t ws_size,
                              hipStream_t stream) {
    int* flag = (int*)d_ws;
    float* base = (float*)d_ws + 4;                 // 16-byte offset (proven)
    float* xl   = base;                             // 294,912 f
    float* xh   = xl + (size_t)BB * CMID * HWSZ;    // 294,912 f
    float2* csn = (float2*)(xh + (size_t)BB * CMID * HWSZ);  // 259,200 float2
    float* alg  = (float*)(csn + NSITE);            // 294,912 f
    // total = 16 + 1,403,136*4 = 5,612,560 B == proven footprint
    float* xl_p1 = alg;           // overlay: dead after k_add; alg rewritten by fold
    float* xh_p1 = (float*)csn;   // overlay: dead after k_add; csn rewritten by comb
    float* thl   = alg;           // overlay: dead after k_comb; alg rewritten by fold
    float* thh   = xl;            // overlay: xl dead after first k_dir

    k_detect<<<1, 1024, 0, stream>>>((const unsigned int*)d_in[0], flag);

    const int g4 = (BB * (CC / 4) * HWSZ + 255) / 256;   // 4608 blocks

    // bf16-input variant (flag==0)
    k_proj_low<bf16, 0><<<2 * PBLK, 64, 0, stream>>>((const bf16*)d_in[1], (const bf16*)d_in[2], xl, xl_p1, flag);
    k_proj_high<bf16, 0><<<2 * PBLK, 64, 0, stream>>>((const bf16*)d_in[0], (const bf16*)d_in[3], xh, xh_p1, flag);
    // fp32-input variant (flag==1)
    k_proj_low<float, 1><<<2 * PBLK, 64, 0, stream>>>((const float*)d_in[1], (const float*)d_in[2], xl, xl_p1, flag);
    k_proj_high<float, 1><<<2 * PBLK, 64, 0, stream>>>((const float*)d_in[0], (const float*)d_in[3], xh, xh_p1, flag);

    k_add<<<(BB * CMID * HWSZ + 255) / 256, 256, 0, stream>>>(xl, xl_p1, xh, xh_p1);

    const int gt = (NSITE + 255) / 256;
    k_dir <<<gt, 256, 0, stream>>>(xl, thl);   // xl consumed here
    k_dir <<<gt, 256, 0, stream>>>(xh, thh);   // thh overlays xl (now dead)
    k_comb<<<gt, 256, 0, stream>>>(thl, thh, csn);

    k_fold_int   <<<(NINT + 255) / 256, 256, 0, stream>>>(xh, csn, alg);
    k_fold_border<<<(BB * CMID * HWSZ + 255) / 256, 256, 0, stream>>>(xh, csn, alg);

    k_final<bf16, bf16, 0><<<g4, 256, 0, stream>>>((const bf16*)d_in[1], (const bf16*)d_in[0], alg,
                                                   (const bf16*)d_in[4], (const bf16*)d_in[5],
                                                   (bf16*)d_out, flag);
    k_final<float, float, 1><<<g4, 256, 0, stream>>>((const float*)d_in[1], (const float*)d_in[0], alg,
                                                     (const float*)d_in[4], (const float*)d_in[5],
                                                     (float*)d_out, flag);
}